// Round 1
// baseline (2029.392 us; speedup 1.0000x reference)
//
#include <hip/hip_runtime.h>
#include <hip/hip_bf16.h>

#define N_USER 100000
#define N_ITEM 100000
#define EMB_DIM 64
#define NEG_SLOPE 0.2f

// ---- float <-> order-preserving uint (for atomicMax on floats) ----
__device__ __forceinline__ unsigned int float_to_ordered(float f) {
    unsigned int u = __float_as_uint(f);
    return (u & 0x80000000u) ? ~u : (u | 0x80000000u);
}
__device__ __forceinline__ float ordered_to_float(unsigned int k) {
    unsigned int u = (k & 0x80000000u) ? (k & 0x7fffffffu) : ~k;
    return __uint_as_float(u);
}

// Each edge is handled by a 16-lane group; lane loads float4 of src row and
// dst row, dot4, then butterfly-reduce across the 16 lanes (masks 1,2,4,8
// stay within the aligned group). All 16 lanes end with the full dot.
__device__ __forceinline__ float edge_score(const float* __restrict__ src_emb,
                                            const float* __restrict__ dst_emb,
                                            int si, int di, int sub,
                                            float4& a_out) {
    const float4 a = *reinterpret_cast<const float4*>(src_emb + (size_t)si * EMB_DIM + sub * 4);
    const float4 b = *reinterpret_cast<const float4*>(dst_emb + (size_t)di * EMB_DIM + sub * 4);
    a_out = a;
    float p = a.x * b.x + a.y * b.y + a.z * b.z + a.w * b.w;
    p += __shfl_xor(p, 1);
    p += __shfl_xor(p, 2);
    p += __shfl_xor(p, 4);
    p += __shfl_xor(p, 8);
    // leaky relu
    return p >= 0.0f ? p : NEG_SLOPE * p;
}

// Pass 1: per-edge score -> segment max over dst (ordered-uint atomicMax)
__global__ void score_max_kernel(const float* __restrict__ src_emb,
                                 const float* __restrict__ dst_emb,
                                 const int* __restrict__ src,
                                 const int* __restrict__ dst,
                                 unsigned int* __restrict__ mkey,
                                 int n_edges) {
    int t = blockIdx.x * blockDim.x + threadIdx.x;
    int e = t >> 4;
    int sub = t & 15;
    if (e >= n_edges) return;
    int si = src[e], di = dst[e];
    float4 av;
    float p = edge_score(src_emb, dst_emb, si, di, sub, av);
    if (sub == 0) {
        atomicMax(&mkey[di], float_to_ordered(p));
    }
}

// Pass 2: w = exp(e - m[dst]) -> segment sum over dst
__global__ void score_sum_kernel(const float* __restrict__ src_emb,
                                 const float* __restrict__ dst_emb,
                                 const int* __restrict__ src,
                                 const int* __restrict__ dst,
                                 const unsigned int* __restrict__ mkey,
                                 float* __restrict__ ssum,
                                 int n_edges) {
    int t = blockIdx.x * blockDim.x + threadIdx.x;
    int e = t >> 4;
    int sub = t & 15;
    if (e >= n_edges) return;
    int si = src[e], di = dst[e];
    float4 av;
    float p = edge_score(src_emb, dst_emb, si, di, sub, av);
    if (sub == 0) {
        float m = ordered_to_float(mkey[di]);
        atomicAdd(&ssum[di], __expf(p - m) == 0.0f ? expf(p - m) : expf(p - m));
    }
}

// Pass 3: a = w / s[dst]; out[dst] += a * h_src  (each lane scatters 4 dims)
__global__ void scatter_out_kernel(const float* __restrict__ src_emb,
                                   const float* __restrict__ dst_emb,
                                   const int* __restrict__ src,
                                   const int* __restrict__ dst,
                                   const unsigned int* __restrict__ mkey,
                                   const float* __restrict__ ssum,
                                   float* __restrict__ out,
                                   int n_edges) {
    int t = blockIdx.x * blockDim.x + threadIdx.x;
    int e = t >> 4;
    int sub = t & 15;
    if (e >= n_edges) return;
    int si = src[e], di = dst[e];
    float4 av;
    float p = edge_score(src_emb, dst_emb, si, di, sub, av);
    float m = ordered_to_float(mkey[di]);
    float s = ssum[di];
    float a = expf(p - m) / s;
    float* o = out + (size_t)di * EMB_DIM + sub * 4;
    atomicAdd(o + 0, a * av.x);
    atomicAdd(o + 1, a * av.y);
    atomicAdd(o + 2, a * av.z);
    atomicAdd(o + 3, a * av.w);
}

extern "C" void kernel_launch(void* const* d_in, const int* in_sizes, int n_in,
                              void* d_out, int out_size, void* d_ws, size_t ws_size,
                              hipStream_t stream) {
    const float* user_emb = (const float*)d_in[0];
    const float* item_emb = (const float*)d_in[1];
    const int* ui_src = (const int*)d_in[2];
    const int* ui_dst = (const int*)d_in[3];
    const int* iu_src = (const int*)d_in[4];
    const int* iu_dst = (const int*)d_in[5];

    float* out = (float*)d_out;
    float* item_out = out;                       // [N_ITEM, 64]
    float* user_out = out + (size_t)N_ITEM * EMB_DIM;  // [N_USER, 64]

    unsigned char* ws = (unsigned char*)d_ws;
    unsigned int* mkey_item = (unsigned int*)(ws);
    float*        s_item    = (float*)(ws + (size_t)N_ITEM * 4);
    unsigned int* mkey_user = (unsigned int*)(ws + (size_t)N_ITEM * 8);
    float*        s_user    = (float*)(ws + (size_t)N_ITEM * 8 + (size_t)N_USER * 4);

    const int E_ui = in_sizes[2];
    const int E_iu = in_sizes[4];

    // zero output + workspace (mkey init 0 == ordered encoding lower than any
    // real float; s init 0)
    hipMemsetAsync(d_out, 0, (size_t)out_size * sizeof(float), stream);
    hipMemsetAsync(d_ws, 0, (size_t)(N_ITEM + N_USER) * 2 * 4, stream);

    const int threads = 256;
    int blocks_ui = (E_ui * 16 + threads - 1) / threads;
    int blocks_iu = (E_iu * 16 + threads - 1) / threads;

    // Pass 1: segment max
    score_max_kernel<<<blocks_ui, threads, 0, stream>>>(user_emb, item_emb, ui_src, ui_dst, mkey_item, E_ui);
    score_max_kernel<<<blocks_iu, threads, 0, stream>>>(item_emb, user_emb, iu_src, iu_dst, mkey_user, E_iu);
    // Pass 2: segment sum of exp
    score_sum_kernel<<<blocks_ui, threads, 0, stream>>>(user_emb, item_emb, ui_src, ui_dst, mkey_item, s_item, E_ui);
    score_sum_kernel<<<blocks_iu, threads, 0, stream>>>(item_emb, user_emb, iu_src, iu_dst, mkey_user, s_user, E_iu);
    // Pass 3: weighted scatter
    scatter_out_kernel<<<blocks_ui, threads, 0, stream>>>(user_emb, item_emb, ui_src, ui_dst, mkey_item, s_item, item_out, E_ui);
    scatter_out_kernel<<<blocks_iu, threads, 0, stream>>>(item_emb, user_emb, iu_src, iu_dst, mkey_user, s_user, user_out, E_iu);
}

// Round 2
// 342.677 us; speedup vs baseline: 5.9222x; 5.9222x over previous
//
#include <hip/hip_runtime.h>
#include <hip/hip_bf16.h>

#define N_USER 100000
#define N_ITEM 100000
#define EMB_DIM 64
#define NEG_SLOPE 0.2f

// ---------------- CSR build: histogram -> exclusive scan -> scatter ----------

__global__ void hist_kernel(const int* __restrict__ dst, int* __restrict__ count, int E) {
    int e = blockIdx.x * blockDim.x + threadIdx.x;
    if (e < E) atomicAdd(&count[dst[e]], 1);
}

// Per-block (1024) Hillis-Steele scan; writes exclusive scan + block total.
__global__ void scan1_kernel(const int* __restrict__ in, int* __restrict__ out,
                             int* __restrict__ bsum, int n) {
    __shared__ int tmp[1024];
    int i = blockIdx.x * 1024 + threadIdx.x;
    int v = (i < n) ? in[i] : 0;
    tmp[threadIdx.x] = v;
    __syncthreads();
    int run = v;
    for (int off = 1; off < 1024; off <<= 1) {
        int add = (threadIdx.x >= (unsigned)off) ? tmp[threadIdx.x - off] : 0;
        __syncthreads();
        run += add;
        tmp[threadIdx.x] = run;
        __syncthreads();
    }
    if (i < n) out[i] = run - v;           // exclusive
    if (threadIdx.x == 1023) bsum[blockIdx.x] = run;  // block total
}

// Single-block exclusive scan over block totals (nb <= 1024).
__global__ void scan2_kernel(int* __restrict__ bsum, int nb) {
    __shared__ int tmp[1024];
    int v = (threadIdx.x < (unsigned)nb) ? bsum[threadIdx.x] : 0;
    tmp[threadIdx.x] = v;
    __syncthreads();
    int run = v;
    for (int off = 1; off < 1024; off <<= 1) {
        int add = (threadIdx.x >= (unsigned)off) ? tmp[threadIdx.x - off] : 0;
        __syncthreads();
        run += add;
        tmp[threadIdx.x] = run;
        __syncthreads();
    }
    if (threadIdx.x < (unsigned)nb) bsum[threadIdx.x] = run - v;
}

// Add block offsets; also init cursor = offset for the scatter pass.
__global__ void scan3_kernel(int* __restrict__ offset, const int* __restrict__ bsum,
                             int* __restrict__ cursor, int n) {
    int i = blockIdx.x * 1024 + threadIdx.x;
    if (i < n) {
        int o = offset[i] + bsum[blockIdx.x];
        offset[i] = o;
        cursor[i] = o;
    }
}

// Bucket src indices by dst (order within bucket arbitrary; softmax is
// order-insensitive up to fp rounding).
__global__ void scatter_kernel(const int* __restrict__ src, const int* __restrict__ dst,
                               int* __restrict__ cursor, int* __restrict__ ssrc, int E) {
    int e = blockIdx.x * blockDim.x + threadIdx.x;
    if (e < E) {
        int p = atomicAdd(&cursor[dst[e]], 1);
        ssrc[p] = src[e];
    }
}

// ---------------- Main: one 16-lane group per dst, online softmax -----------
// Each lane owns 4 dims (float4). Dst row lives in registers; per edge we
// gather the src row (256B contiguous), dot + butterfly-reduce across the
// 16-lane group (masks 1,2,4,8 stay within the aligned group), then update the
// running (m, s, acc) flash-attention style. One plain float4 store per lane.
__global__ void gat_row_kernel(const float* __restrict__ src_emb,
                               const float* __restrict__ dst_emb,
                               const int* __restrict__ offset,
                               const int* __restrict__ count,
                               const int* __restrict__ ssrc,
                               float* __restrict__ out, int n_dst) {
    int t = blockIdx.x * blockDim.x + threadIdx.x;
    int d = t >> 4;
    int sub = t & 15;
    if (d >= n_dst) return;
    const float4 b = *reinterpret_cast<const float4*>(dst_emb + (size_t)d * EMB_DIM + sub * 4);
    int beg = offset[d];
    int cnt = count[d];
    float m = -INFINITY, s = 0.0f;
    float4 acc = make_float4(0.f, 0.f, 0.f, 0.f);
    for (int k = 0; k < cnt; ++k) {
        int si = ssrc[beg + k];
        const float4 a = *reinterpret_cast<const float4*>(src_emb + (size_t)si * EMB_DIM + sub * 4);
        float p = a.x * b.x + a.y * b.y + a.z * b.z + a.w * b.w;
        p += __shfl_xor(p, 1);
        p += __shfl_xor(p, 2);
        p += __shfl_xor(p, 4);
        p += __shfl_xor(p, 8);
        p = (p >= 0.0f) ? p : NEG_SLOPE * p;   // leaky relu
        if (p > m) {                            // rescale running state
            float r = __expf(m - p);            // exp(-inf)=0 on first edge
            s *= r;
            acc.x *= r; acc.y *= r; acc.z *= r; acc.w *= r;
            m = p;
        }
        float w = __expf(p - m);
        s += w;
        acc.x += w * a.x; acc.y += w * a.y; acc.z += w * a.z; acc.w += w * a.w;
    }
    float inv = (cnt > 0) ? 1.0f / s : 0.0f;    // empty segment -> zeros
    float4 o = make_float4(acc.x * inv, acc.y * inv, acc.z * inv, acc.w * inv);
    *reinterpret_cast<float4*>(out + (size_t)d * EMB_DIM + sub * 4) = o;
}

// ---------------- Host-side orchestration ------------------------------------

static void run_side(const float* src_emb, const float* dst_emb,
                     const int* src, const int* dst, int E, int n_dst,
                     float* out_side, int* count, int* offset, int* cursor,
                     int* bsum, int* ssrc, hipStream_t stream) {
    const int tb = 256;
    hipMemsetAsync(count, 0, (size_t)n_dst * sizeof(int), stream);
    hist_kernel<<<(E + tb - 1) / tb, tb, 0, stream>>>(dst, count, E);
    int nb = (n_dst + 1023) / 1024;
    scan1_kernel<<<nb, 1024, 0, stream>>>(count, offset, bsum, n_dst);
    scan2_kernel<<<1, 1024, 0, stream>>>(bsum, nb);
    scan3_kernel<<<nb, 1024, 0, stream>>>(offset, bsum, cursor, n_dst);
    scatter_kernel<<<(E + tb - 1) / tb, tb, 0, stream>>>(src, dst, cursor, ssrc, E);
    gat_row_kernel<<<((size_t)n_dst * 16 + tb - 1) / tb, tb, 0, stream>>>(
        src_emb, dst_emb, offset, count, ssrc, out_side, n_dst);
}

extern "C" void kernel_launch(void* const* d_in, const int* in_sizes, int n_in,
                              void* d_out, int out_size, void* d_ws, size_t ws_size,
                              hipStream_t stream) {
    const float* user_emb = (const float*)d_in[0];
    const float* item_emb = (const float*)d_in[1];
    const int* ui_src = (const int*)d_in[2];
    const int* ui_dst = (const int*)d_in[3];
    const int* iu_src = (const int*)d_in[4];
    const int* iu_dst = (const int*)d_in[5];

    float* out = (float*)d_out;
    float* item_out = out;                              // [N_ITEM, 64]
    float* user_out = out + (size_t)N_ITEM * EMB_DIM;   // [N_USER, 64]

    const int E_ui = in_sizes[2];
    const int E_iu = in_sizes[4];
    const int Emax = E_ui > E_iu ? E_ui : E_iu;
    const int Nmax = N_USER > N_ITEM ? N_USER : N_ITEM;

    // ws layout (sides run sequentially on the stream and reuse the buffers):
    int* ws = (int*)d_ws;
    int* count  = ws;
    int* offset = ws + Nmax;
    int* cursor = ws + 2 * (size_t)Nmax;
    int* bsum   = ws + 3 * (size_t)Nmax;
    int* ssrc   = ws + 3 * (size_t)Nmax + 1024;
    (void)ws_size; (void)Emax;

    // side 1: user->item aggregates into item_out
    run_side(user_emb, item_emb, ui_src, ui_dst, E_ui, N_ITEM,
             item_out, count, offset, cursor, bsum, ssrc, stream);
    // side 2: item->user aggregates into user_out
    run_side(item_emb, user_emb, iu_src, iu_dst, E_iu, N_USER,
             user_out, count, offset, cursor, bsum, ssrc, stream);
}

// Round 3
// 148.725 us; speedup vs baseline: 13.6452x; 2.3041x over previous
//
#include <hip/hip_runtime.h>
#include <hip/hip_bf16.h>

#define N_USER 100000
#define N_ITEM 100000
#define EMB_DIM 64
#define NEG_SLOPE 0.2f

#define SHIFT 6              // 64 fine dst per coarse bucket
#define FPB 64               // 1 << SHIFT
#define FMASK 63
#define NB 1563              // ceil(100000 / 64), same for both sides
#define GCAP 1024            // LDS capacity per bucket (avg 640, +15 sigma)
#define BIN_TILE 8192
#define HIST_BLOCKS 128      // per side

struct Side {
    const float* src_emb;
    const float* dst_emb;
    const int*   src;
    const int*   dst;
    int          E;
    int          n_dst;
    int*         ghist;   // [NB] coarse histogram
    int*         off;     // [NB] coarse exclusive offsets
    int*         cur;     // [NB] atomic cursors (init = off)
    int*         pairs;   // [E] packed (src<<SHIFT)|fine, binned by coarse bucket
    float*       out;     // [n_dst, EMB_DIM]
};

// ---------- 1. coarse histogram (LDS-staged) --------------------------------
__global__ void hist_kernel(Side A, Side B, int nbA) {
    Side S; int lb;
    if ((int)blockIdx.x < nbA) { S = A; lb = blockIdx.x; }
    else                       { S = B; lb = blockIdx.x - nbA; }
    __shared__ int h[NB];
    for (int i = threadIdx.x; i < NB; i += blockDim.x) h[i] = 0;
    __syncthreads();
    int stride = HIST_BLOCKS * blockDim.x;
    for (int i = lb * blockDim.x + threadIdx.x; i < S.E; i += stride)
        atomicAdd(&h[S.dst[i] >> SHIFT], 1);
    __syncthreads();
    for (int i = threadIdx.x; i < NB; i += blockDim.x)
        if (h[i]) atomicAdd(&S.ghist[i], h[i]);
}

// ---------- 2. exclusive scan of coarse hist (single block, both sides) -----
__global__ void scan_kernel(Side A, Side B, int nsides) {
    __shared__ int tmp[1024];
    for (int sIdx = 0; sIdx < nsides; ++sIdx) {
        Side S = sIdx ? B : A;
        int t = threadIdx.x;
        int i0 = 2 * t, i1 = 2 * t + 1;
        int v0 = (i0 < NB) ? S.ghist[i0] : 0;
        int v1 = (i1 < NB) ? S.ghist[i1] : 0;
        int ps = v0 + v1;
        tmp[t] = ps;
        __syncthreads();
        int run = ps;
        for (int off = 1; off < 1024; off <<= 1) {
            int add = (t >= off) ? tmp[t - off] : 0;
            __syncthreads();
            run += add;
            tmp[t] = run;
            __syncthreads();
        }
        int base = run - ps;  // exclusive prefix of this thread's pair
        if (i0 < NB) { S.off[i0] = base;      S.cur[i0] = base; }
        if (i1 < NB) { S.off[i1] = base + v0; S.cur[i1] = base + v0; }
        __syncthreads();
    }
}

// ---------- 3. bin edges by coarse bucket (LDS-staged, per-tile) ------------
// Per 8192-edge tile: LDS hist -> one global reservation per touched bucket ->
// write packed (src<<SHIFT)|fine. A bucket's entries from one tile form a
// contiguous run written from a single CU/XCD -> lines merge in its L2.
__global__ void bin_kernel(Side A, Side B, int nbA) {
    Side S; int lb;
    if ((int)blockIdx.x < nbA) { S = A; lb = blockIdx.x; }
    else                       { S = B; lb = blockIdx.x - nbA; }
    __shared__ int h[NB];
    __shared__ int bl[NB];
    int t = threadIdx.x;
    for (int i = t; i < NB; i += blockDim.x) h[i] = 0;
    __syncthreads();
    int beg = lb * BIN_TILE;
    int end = min(beg + BIN_TILE, S.E);
    for (int i = beg + t; i < end; i += blockDim.x)
        atomicAdd(&h[S.dst[i] >> SHIFT], 1);
    __syncthreads();
    for (int i = t; i < NB; i += blockDim.x) {
        int c = h[i];
        bl[i] = c ? atomicAdd(&S.cur[i], c) : 0;
        h[i] = 0;  // reuse as local cursor
    }
    __syncthreads();
    for (int i = beg + t; i < end; i += blockDim.x) {
        int d = S.dst[i];
        int b = d >> SHIFT;
        int r = atomicAdd(&h[b], 1);
        S.pairs[bl[b] + r] = (S.src[i] << SHIFT) | (d & FMASK);
    }
}

// ---------- 4. per-bucket fine sort (LDS) + online-softmax aggregation ------
// One block per coarse bucket. 16-lane group per dst row; each lane owns 4
// dims. Flash-attention-style running (m, s, acc); one plain float4 store.
__global__ void gat_kernel(Side A, Side B, int nbA) {
    Side S; int bucket;
    if ((int)blockIdx.x < nbA) { S = A; bucket = blockIdx.x; }
    else                       { S = B; bucket = blockIdx.x - nbA; }
    __shared__ int fh[FPB], fcur[FPB], foff[FPB], sc[FPB];
    __shared__ int fsrc[GCAP];
    int t = threadIdx.x;
    if (t < FPB) fh[t] = 0;
    __syncthreads();
    int beg = S.off[bucket];
    int cnt = S.ghist[bucket];
    for (int i = t; i < cnt; i += 256)
        atomicAdd(&fh[S.pairs[beg + i] & FMASK], 1);
    __syncthreads();
    if (t < FPB) sc[t] = fh[t];
    __syncthreads();
    for (int off = 1; off < FPB; off <<= 1) {
        int v = 0;
        if (t < FPB) v = sc[t] + ((t >= off) ? sc[t - off] : 0);
        __syncthreads();
        if (t < FPB) sc[t] = v;
        __syncthreads();
    }
    if (t < FPB) { foff[t] = sc[t] - fh[t]; fcur[t] = sc[t] - fh[t]; }
    __syncthreads();
    for (int i = t; i < cnt; i += 256) {
        int v = S.pairs[beg + i];
        int r = atomicAdd(&fcur[v & FMASK], 1);
        if (r < GCAP) fsrc[r] = v >> SHIFT;
    }
    __syncthreads();
    int g = t >> 4, sub = t & 15;
    for (int f = g; f < FPB; f += 16) {
        int d = (bucket << SHIFT) + f;
        if (d >= S.n_dst) continue;
        const float4 bv = *reinterpret_cast<const float4*>(
            S.dst_emb + (size_t)d * EMB_DIM + sub * 4);
        int s0 = foff[f], cf = fh[f];
        float m = -INFINITY, ssum = 0.0f;
        float4 acc = make_float4(0.f, 0.f, 0.f, 0.f);
        for (int k = 0; k < cf; ++k) {
            int si = fsrc[s0 + k];
            const float4 a = *reinterpret_cast<const float4*>(
                S.src_emb + (size_t)si * EMB_DIM + sub * 4);
            float p = a.x * bv.x + a.y * bv.y + a.z * bv.z + a.w * bv.w;
            p += __shfl_xor(p, 1);
            p += __shfl_xor(p, 2);
            p += __shfl_xor(p, 4);
            p += __shfl_xor(p, 8);
            p = (p >= 0.0f) ? p : NEG_SLOPE * p;
            if (p > m) {
                float r = __expf(m - p);  // exp(-inf)=0 on first edge
                ssum *= r;
                acc.x *= r; acc.y *= r; acc.z *= r; acc.w *= r;
                m = p;
            }
            float w = __expf(p - m);
            ssum += w;
            acc.x += w * a.x; acc.y += w * a.y; acc.z += w * a.z; acc.w += w * a.w;
        }
        float inv = (cf > 0) ? 1.0f / ssum : 0.0f;
        float4 o = make_float4(acc.x * inv, acc.y * inv, acc.z * inv, acc.w * inv);
        *reinterpret_cast<float4*>(S.out + (size_t)d * EMB_DIM + sub * 4) = o;
    }
}

// ---------- host orchestration ----------------------------------------------
extern "C" void kernel_launch(void* const* d_in, const int* in_sizes, int n_in,
                              void* d_out, int out_size, void* d_ws, size_t ws_size,
                              hipStream_t stream) {
    const float* user_emb = (const float*)d_in[0];
    const float* item_emb = (const float*)d_in[1];
    const int* ui_src = (const int*)d_in[2];
    const int* ui_dst = (const int*)d_in[3];
    const int* iu_src = (const int*)d_in[4];
    const int* iu_dst = (const int*)d_in[5];

    float* out = (float*)d_out;
    float* item_out = out;                              // [N_ITEM, 64]
    float* user_out = out + (size_t)N_ITEM * EMB_DIM;   // [N_USER, 64]

    const int E0 = in_sizes[2];
    const int E1 = in_sizes[4];

    Side A, B;
    A.src_emb = user_emb; A.dst_emb = item_emb; A.src = ui_src; A.dst = ui_dst;
    A.E = E0; A.n_dst = N_ITEM; A.out = item_out;
    B.src_emb = item_emb; B.dst_emb = user_emb; B.src = iu_src; B.dst = iu_dst;
    B.E = E1; B.n_dst = N_USER; B.out = user_out;

    int* w = (int*)d_ws;
    size_t need_fused = (size_t)(6 * NB + E0 + E1) * 4;

    if (ws_size >= need_fused) {
        // fused layout: [ghist0 | ghist1 | off0 | cur0 | off1 | cur1 | pairs0 | pairs1]
        A.ghist = w;            B.ghist = w + NB;
        A.off   = w + 2 * NB;   A.cur = w + 3 * NB;
        B.off   = w + 4 * NB;   B.cur = w + 5 * NB;
        A.pairs = w + 6 * NB;   B.pairs = A.pairs + E0;

        hipMemsetAsync(A.ghist, 0, 2 * NB * sizeof(int), stream);
        hist_kernel<<<2 * HIST_BLOCKS, 256, 0, stream>>>(A, B, HIST_BLOCKS);
        scan_kernel<<<1, 1024, 0, stream>>>(A, B, 2);
        int tb0 = (E0 + BIN_TILE - 1) / BIN_TILE;
        int tb1 = (E1 + BIN_TILE - 1) / BIN_TILE;
        bin_kernel<<<tb0 + tb1, 512, 0, stream>>>(A, B, tb0);
        gat_kernel<<<2 * NB, 256, 0, stream>>>(A, B, NB);
    } else {
        // sequential fallback: both sides share one workspace region
        Side sides[2] = {A, B};
        for (int s = 0; s < 2; ++s) {
            Side S = sides[s];
            S.ghist = w; S.off = w + NB; S.cur = w + 2 * NB; S.pairs = w + 3 * NB;
            hipMemsetAsync(S.ghist, 0, NB * sizeof(int), stream);
            hist_kernel<<<HIST_BLOCKS, 256, 0, stream>>>(S, S, HIST_BLOCKS);
            scan_kernel<<<1, 1024, 0, stream>>>(S, S, 1);
            int tb = (S.E + BIN_TILE - 1) / BIN_TILE;
            bin_kernel<<<tb, 512, 0, stream>>>(S, S, tb);
            gat_kernel<<<NB, 256, 0, stream>>>(S, S, NB);
        }
    }
}

// Round 4
// 139.818 us; speedup vs baseline: 14.5145x; 1.0637x over previous
//
#include <hip/hip_runtime.h>
#include <hip/hip_bf16.h>

#define N_USER 100000
#define N_ITEM 100000
#define EMB_DIM 64
#define NEG_SLOPE 0.2f

#define SHIFT 6              // 64 fine dst per coarse bucket
#define FPB 64               // 1 << SHIFT
#define FMASK 63
#define NB 1563              // ceil(100000 / 64), same for both sides
#define GCAP 1024            // LDS capacity per bucket (avg 640; max ~750)
#define BIN_TILE 8192
#define HIST_BLOCKS 128      // per side

struct Side {
    const float* src_emb;
    const float* dst_emb;
    const int*   src;
    const int*   dst;
    int          E;
    int          n_dst;
    int*         ghist;   // [NB] coarse histogram
    int*         off;     // [NB] coarse exclusive offsets
    int*         cur;     // [NB] atomic cursors (init = off)
    int*         pairs;   // [E] packed (src<<SHIFT)|fine, binned by coarse bucket
    float*       out;     // [n_dst, EMB_DIM]
};

// ---- DPP 16-lane all-reduce step: x += row_ror<N>(x). VALU-pipe (~4-8cy)
// instead of ds_permute (~30-60cy). row_ror ctrl = 0x120|N; rotate-reduce with
// N=1,2,4,8 leaves every lane of the 16-lane row holding the full sum.
template <int CTRL>
__device__ __forceinline__ float dpp_add(float x) {
    int v = __builtin_amdgcn_update_dpp(0, __float_as_int(x), CTRL, 0xf, 0xf, true);
    return x + __int_as_float(v);
}
__device__ __forceinline__ float row16_allsum(float p) {
    p = dpp_add<0x121>(p);  // ror:1
    p = dpp_add<0x122>(p);  // ror:2
    p = dpp_add<0x124>(p);  // ror:4
    p = dpp_add<0x128>(p);  // ror:8
    return p;
}

// ---------- 1. coarse histogram (LDS-staged) --------------------------------
__global__ void hist_kernel(Side A, Side B, int nbA) {
    Side S; int lb;
    if ((int)blockIdx.x < nbA) { S = A; lb = blockIdx.x; }
    else                       { S = B; lb = blockIdx.x - nbA; }
    __shared__ int h[NB];
    for (int i = threadIdx.x; i < NB; i += blockDim.x) h[i] = 0;
    __syncthreads();
    int stride = HIST_BLOCKS * blockDim.x;
    for (int i = lb * blockDim.x + threadIdx.x; i < S.E; i += stride)
        atomicAdd(&h[S.dst[i] >> SHIFT], 1);
    __syncthreads();
    for (int i = threadIdx.x; i < NB; i += blockDim.x)
        if (h[i]) atomicAdd(&S.ghist[i], h[i]);
}

// ---------- 2. exclusive scan of coarse hist (single block, both sides) -----
__global__ void scan_kernel(Side A, Side B, int nsides) {
    __shared__ int tmp[1024];
    for (int sIdx = 0; sIdx < nsides; ++sIdx) {
        Side S = sIdx ? B : A;
        int t = threadIdx.x;
        int i0 = 2 * t, i1 = 2 * t + 1;
        int v0 = (i0 < NB) ? S.ghist[i0] : 0;
        int v1 = (i1 < NB) ? S.ghist[i1] : 0;
        int ps = v0 + v1;
        tmp[t] = ps;
        __syncthreads();
        int run = ps;
        for (int off = 1; off < 1024; off <<= 1) {
            int add = (t >= off) ? tmp[t - off] : 0;
            __syncthreads();
            run += add;
            tmp[t] = run;
            __syncthreads();
        }
        int base = run - ps;  // exclusive prefix of this thread's pair
        if (i0 < NB) { S.off[i0] = base;      S.cur[i0] = base; }
        if (i1 < NB) { S.off[i1] = base + v0; S.cur[i1] = base + v0; }
        __syncthreads();
    }
}

// ---------- 3. bin edges by coarse bucket (LDS-staged, per-tile) ------------
__global__ void bin_kernel(Side A, Side B, int nbA) {
    Side S; int lb;
    if ((int)blockIdx.x < nbA) { S = A; lb = blockIdx.x; }
    else                       { S = B; lb = blockIdx.x - nbA; }
    __shared__ int h[NB];
    __shared__ int bl[NB];
    int t = threadIdx.x;
    for (int i = t; i < NB; i += blockDim.x) h[i] = 0;
    __syncthreads();
    int beg = lb * BIN_TILE;
    int end = min(beg + BIN_TILE, S.E);
    for (int i = beg + t; i < end; i += blockDim.x)
        atomicAdd(&h[S.dst[i] >> SHIFT], 1);
    __syncthreads();
    for (int i = t; i < NB; i += blockDim.x) {
        int c = h[i];
        bl[i] = c ? atomicAdd(&S.cur[i], c) : 0;
        h[i] = 0;  // reuse as local cursor
    }
    __syncthreads();
    for (int i = beg + t; i < end; i += blockDim.x) {
        int d = S.dst[i];
        int b = d >> SHIFT;
        int r = atomicAdd(&h[b], 1);
        S.pairs[bl[b] + r] = (S.src[i] << SHIFT) | (d & FMASK);
    }
}

// ---------- 4. per-bucket fine sort (LDS) + online-softmax aggregation ------
// One block per coarse bucket; 16-lane group per dst row, lane owns 4 dims.
// DPP rotate-reduce for the dot; src-row gather software-pipelined one edge
// ahead so L2/L3 latency hides under the softmax chain.
__global__ void gat_kernel(Side A, Side B, int nbA) {
    Side S; int bucket;
    if ((int)blockIdx.x < nbA) { S = A; bucket = blockIdx.x; }
    else                       { S = B; bucket = blockIdx.x - nbA; }
    __shared__ int fh[FPB], fcur[FPB], foff[FPB], sc[FPB];
    __shared__ int fsrc[GCAP];
    int t = threadIdx.x;
    if (t < FPB) fh[t] = 0;
    __syncthreads();
    int beg = S.off[bucket];
    int cnt = S.ghist[bucket];
    for (int i = t; i < cnt; i += 256)
        atomicAdd(&fh[S.pairs[beg + i] & FMASK], 1);
    __syncthreads();
    if (t < FPB) sc[t] = fh[t];
    __syncthreads();
    for (int off = 1; off < FPB; off <<= 1) {
        int v = 0;
        if (t < FPB) v = sc[t] + ((t >= off) ? sc[t - off] : 0);
        __syncthreads();
        if (t < FPB) sc[t] = v;
        __syncthreads();
    }
    if (t < FPB) { foff[t] = sc[t] - fh[t]; fcur[t] = sc[t] - fh[t]; }
    __syncthreads();
    for (int i = t; i < cnt; i += 256) {
        int v = S.pairs[beg + i];
        int r = atomicAdd(&fcur[v & FMASK], 1);
        if (r < GCAP) fsrc[r] = v >> SHIFT;
    }
    __syncthreads();
    int g = t >> 4, sub = t & 15;
    for (int f = g; f < FPB; f += 16) {
        int d = (bucket << SHIFT) + f;
        if (d >= S.n_dst) continue;
        const float4 bv = *reinterpret_cast<const float4*>(
            S.dst_emb + (size_t)d * EMB_DIM + sub * 4);
        int s0 = foff[f], cf = fh[f];
        float m = -INFINITY, ssum = 0.0f;
        float4 acc = make_float4(0.f, 0.f, 0.f, 0.f);
        if (cf > 0) {
            int si = fsrc[s0];
            float4 a = *reinterpret_cast<const float4*>(
                S.src_emb + (size_t)si * EMB_DIM + sub * 4);
            for (int k = 0; k < cf; ++k) {
                float4 ac = a;
                if (k + 1 < cf) {                      // prefetch next edge
                    int sn = fsrc[s0 + k + 1];
                    a = *reinterpret_cast<const float4*>(
                        S.src_emb + (size_t)sn * EMB_DIM + sub * 4);
                }
                float p = ac.x * bv.x + ac.y * bv.y + ac.z * bv.z + ac.w * bv.w;
                p = row16_allsum(p);
                p = (p >= 0.0f) ? p : NEG_SLOPE * p;   // leaky relu
                if (p > m) {                            // rescale running state
                    float r = __expf(m - p);            // exp(-inf)=0 first edge
                    ssum *= r;
                    acc.x *= r; acc.y *= r; acc.z *= r; acc.w *= r;
                    m = p;
                }
                float w = __expf(p - m);
                ssum += w;
                acc.x += w * ac.x; acc.y += w * ac.y;
                acc.z += w * ac.z; acc.w += w * ac.w;
            }
        }
        float inv = (cf > 0) ? 1.0f / ssum : 0.0f;
        float4 o = make_float4(acc.x * inv, acc.y * inv, acc.z * inv, acc.w * inv);
        *reinterpret_cast<float4*>(S.out + (size_t)d * EMB_DIM + sub * 4) = o;
    }
}

// ---------- host orchestration ----------------------------------------------
extern "C" void kernel_launch(void* const* d_in, const int* in_sizes, int n_in,
                              void* d_out, int out_size, void* d_ws, size_t ws_size,
                              hipStream_t stream) {
    const float* user_emb = (const float*)d_in[0];
    const float* item_emb = (const float*)d_in[1];
    const int* ui_src = (const int*)d_in[2];
    const int* ui_dst = (const int*)d_in[3];
    const int* iu_src = (const int*)d_in[4];
    const int* iu_dst = (const int*)d_in[5];

    float* out = (float*)d_out;
    float* item_out = out;                              // [N_ITEM, 64]
    float* user_out = out + (size_t)N_ITEM * EMB_DIM;   // [N_USER, 64]

    const int E0 = in_sizes[2];
    const int E1 = in_sizes[4];

    Side A, B;
    A.src_emb = user_emb; A.dst_emb = item_emb; A.src = ui_src; A.dst = ui_dst;
    A.E = E0; A.n_dst = N_ITEM; A.out = item_out;
    B.src_emb = item_emb; B.dst_emb = user_emb; B.src = iu_src; B.dst = iu_dst;
    B.E = E1; B.n_dst = N_USER; B.out = user_out;

    int* w = (int*)d_ws;
    size_t need_fused = (size_t)(6 * NB + E0 + E1) * 4;

    if (ws_size >= need_fused) {
        // fused layout: [ghist0 | ghist1 | off0 | cur0 | off1 | cur1 | pairs0 | pairs1]
        A.ghist = w;            B.ghist = w + NB;
        A.off   = w + 2 * NB;   A.cur = w + 3 * NB;
        B.off   = w + 4 * NB;   B.cur = w + 5 * NB;
        A.pairs = w + 6 * NB;   B.pairs = A.pairs + E0;

        hipMemsetAsync(A.ghist, 0, 2 * NB * sizeof(int), stream);
        hist_kernel<<<2 * HIST_BLOCKS, 256, 0, stream>>>(A, B, HIST_BLOCKS);
        scan_kernel<<<1, 1024, 0, stream>>>(A, B, 2);
        int tb0 = (E0 + BIN_TILE - 1) / BIN_TILE;
        int tb1 = (E1 + BIN_TILE - 1) / BIN_TILE;
        bin_kernel<<<tb0 + tb1, 512, 0, stream>>>(A, B, tb0);
        gat_kernel<<<2 * NB, 256, 0, stream>>>(A, B, NB);
    } else {
        // sequential fallback: both sides share one workspace region
        Side sides[2] = {A, B};
        for (int s = 0; s < 2; ++s) {
            Side S = sides[s];
            S.ghist = w; S.off = w + NB; S.cur = w + 2 * NB; S.pairs = w + 3 * NB;
            hipMemsetAsync(S.ghist, 0, NB * sizeof(int), stream);
            hist_kernel<<<HIST_BLOCKS, 256, 0, stream>>>(S, S, HIST_BLOCKS);
            scan_kernel<<<1, 1024, 0, stream>>>(S, S, 1);
            int tb = (S.E + BIN_TILE - 1) / BIN_TILE;
            bin_kernel<<<tb, 512, 0, stream>>>(S, S, tb);
            gat_kernel<<<NB, 256, 0, stream>>>(S, S, NB);
        }
    }
}